// Round 1
// baseline (7277.837 us; speedup 1.0000x reference)
//
#include <hip/hip_runtime.h>
#include <math.h>

// ---------------------------------------------------------------------------
// TGN forward, fp32 baseline.
// Kernel A: per-edge message MLP + atomic scatter-add into aggr/counts
// Kernel B: GRU memory update over all nodes
// Kernel C: embedding MLPs (src/dst) + dot product
// ---------------------------------------------------------------------------

// ------------------------- Kernel A: edge messages -------------------------
// block = 128 threads, tile = 32 edges.
// LDS xs: 32 rows x 324 (320 + pad4) floats; h1 reuses same buffer (stride 132).
__global__ __launch_bounds__(128) void k_edge_msg(
    const int* __restrict__ src, const int* __restrict__ dst,
    const float* __restrict__ ef, const float* __restrict__ ts,
    const float* __restrict__ mem, const float* __restrict__ tw, const float* __restrict__ tb,
    const float* __restrict__ w1, const float* __restrict__ b1,
    const float* __restrict__ w2, const float* __restrict__ b2,
    float* __restrict__ aggr, float* __restrict__ cnt, int E)
{
    __shared__ float xs[32 * 324];
    const int t  = threadIdx.x;
    const int e0 = blockIdx.x * 32;

    // counts scatter (1 per endpoint)
    if (t < 32) {
        int ge = e0 + t;
        if (ge < E) {
            atomicAdd(&cnt[src[ge]], 1.0f);
            atomicAdd(&cnt[dst[ge]], 1.0f);
        }
    }

    // stage x = [src_mem(128) | dst_mem(128) | edge_feat(32) | time_enc(32)]
    for (int idx = t; idx < 32 * 320; idx += 128) {
        int e = idx / 320;
        int k = idx - e * 320;
        int ge = e0 + e;
        float v = 0.0f;
        if (ge < E) {
            if (k < 128)       v = mem[src[ge] * 128 + k];
            else if (k < 256)  v = mem[dst[ge] * 128 + (k - 128)];
            else if (k < 288)  v = ef[ge * 32 + (k - 256)];
            else { int q = k - 288; v = cosf(ts[ge] * tw[q] + tb[q]); }
        }
        xs[e * 324 + k] = v;
    }
    __syncthreads();

    const int j0 = (t & 15) * 8;     // 16 thread-groups cover 128 output cols
    const int eb = (t >> 4) * 4;     // 8 groups x 4 edges = 32 edges

    // GEMM1: h1 = relu(x @ w1 + b1), K=320
    float acc[4][8];
    #pragma unroll
    for (int j = 0; j < 8; ++j) {
        float b = b1[j0 + j];
        #pragma unroll
        for (int i = 0; i < 4; ++i) acc[i][j] = b;
    }
    for (int k = 0; k < 320; k += 4) {
        float4 xv[4];
        #pragma unroll
        for (int i = 0; i < 4; ++i) xv[i] = *(const float4*)&xs[(eb + i) * 324 + k];
        #pragma unroll
        for (int kk = 0; kk < 4; ++kk) {
            const float4 wa = *(const float4*)&w1[(k + kk) * 128 + j0];
            const float4 wb = *(const float4*)&w1[(k + kk) * 128 + j0 + 4];
            #pragma unroll
            for (int i = 0; i < 4; ++i) {
                const float x = ((const float*)&xv[i])[kk];
                acc[i][0] = fmaf(x, wa.x, acc[i][0]);
                acc[i][1] = fmaf(x, wa.y, acc[i][1]);
                acc[i][2] = fmaf(x, wa.z, acc[i][2]);
                acc[i][3] = fmaf(x, wa.w, acc[i][3]);
                acc[i][4] = fmaf(x, wb.x, acc[i][4]);
                acc[i][5] = fmaf(x, wb.y, acc[i][5]);
                acc[i][6] = fmaf(x, wb.z, acc[i][6]);
                acc[i][7] = fmaf(x, wb.w, acc[i][7]);
            }
        }
    }
    __syncthreads();   // all reads of xs done; reuse buffer for h1 (stride 132)
    #pragma unroll
    for (int i = 0; i < 4; ++i)
        #pragma unroll
        for (int j = 0; j < 8; ++j)
            xs[(eb + i) * 132 + (j0 + j)] = fmaxf(acc[i][j], 0.0f);
    __syncthreads();

    // GEMM2: msg = h1 @ w2 + b2, K=128
    float acc2[4][8];
    #pragma unroll
    for (int j = 0; j < 8; ++j) {
        float b = b2[j0 + j];
        #pragma unroll
        for (int i = 0; i < 4; ++i) acc2[i][j] = b;
    }
    for (int k = 0; k < 128; k += 4) {
        float4 hv[4];
        #pragma unroll
        for (int i = 0; i < 4; ++i) hv[i] = *(const float4*)&xs[(eb + i) * 132 + k];
        #pragma unroll
        for (int kk = 0; kk < 4; ++kk) {
            const float4 wa = *(const float4*)&w2[(k + kk) * 128 + j0];
            const float4 wb = *(const float4*)&w2[(k + kk) * 128 + j0 + 4];
            #pragma unroll
            for (int i = 0; i < 4; ++i) {
                const float h = ((const float*)&hv[i])[kk];
                acc2[i][0] = fmaf(h, wa.x, acc2[i][0]);
                acc2[i][1] = fmaf(h, wa.y, acc2[i][1]);
                acc2[i][2] = fmaf(h, wa.z, acc2[i][2]);
                acc2[i][3] = fmaf(h, wa.w, acc2[i][3]);
                acc2[i][4] = fmaf(h, wb.x, acc2[i][4]);
                acc2[i][5] = fmaf(h, wb.y, acc2[i][5]);
                acc2[i][6] = fmaf(h, wb.z, acc2[i][6]);
                acc2[i][7] = fmaf(h, wb.w, acc2[i][7]);
            }
        }
    }

    // scatter msg into aggr at both endpoints
    #pragma unroll
    for (int i = 0; i < 4; ++i) {
        int ge = e0 + eb + i;
        if (ge < E) {
            int sb = src[ge] * 128 + j0;
            int db = dst[ge] * 128 + j0;
            #pragma unroll
            for (int j = 0; j < 8; ++j) {
                atomicAdd(&aggr[sb + j], acc2[i][j]);
                atomicAdd(&aggr[db + j], acc2[i][j]);
            }
        }
    }
}

// ------------------------- Kernel B: GRU update ----------------------------
// block = 128 threads, tile = 8 nodes. Thread t computes output rows t, t+128,
// t+256 of both gi and gh for all 8 nodes.
__global__ __launch_bounds__(128) void k_gru(
    const float* __restrict__ aggr, const float* __restrict__ cnt,
    const float* __restrict__ mem,
    const float* __restrict__ wih, const float* __restrict__ whh,
    const float* __restrict__ bih, const float* __restrict__ bhh,
    float* __restrict__ newmem, int N)
{
    __shared__ float sm[8 * 132];
    __shared__ float sh[8 * 132];
    __shared__ float sgi[8 * 384];
    __shared__ float sgh[8 * 384];
    __shared__ float scnt[8];
    const int t  = threadIdx.x;
    const int n0 = blockIdx.x * 8;

    if (t < 8) scnt[t] = (n0 + t < N) ? cnt[n0 + t] : 0.0f;
    for (int idx = t; idx < 8 * 128; idx += 128) {
        int n = idx >> 7, k = idx & 127;
        float m = 0.0f, h = 0.0f;
        if (n0 + n < N) {
            float c = cnt[n0 + n];
            m = aggr[(n0 + n) * 128 + k] / fmaxf(c, 1e-9f);
            h = mem[(n0 + n) * 128 + k];
        }
        sm[n * 132 + k] = m;
        sh[n * 132 + k] = h;
    }
    __syncthreads();

    const int r = t;
    float agi[3][8], agh[3][8];
    #pragma unroll
    for (int rr = 0; rr < 3; ++rr) {
        float bi = bih[r + rr * 128];
        float bh = bhh[r + rr * 128];
        #pragma unroll
        for (int n = 0; n < 8; ++n) { agi[rr][n] = bi; agh[rr][n] = bh; }
    }
    for (int k = 0; k < 128; k += 4) {
        float4 mv[8], hv[8];
        #pragma unroll
        for (int n = 0; n < 8; ++n) {
            mv[n] = *(const float4*)&sm[n * 132 + k];
            hv[n] = *(const float4*)&sh[n * 132 + k];
        }
        #pragma unroll
        for (int rr = 0; rr < 3; ++rr) {
            const float4 wi = *(const float4*)&wih[(r + rr * 128) * 128 + k];
            const float4 wh = *(const float4*)&whh[(r + rr * 128) * 128 + k];
            #pragma unroll
            for (int n = 0; n < 8; ++n) {
                agi[rr][n] = fmaf(mv[n].x, wi.x, agi[rr][n]);
                agi[rr][n] = fmaf(mv[n].y, wi.y, agi[rr][n]);
                agi[rr][n] = fmaf(mv[n].z, wi.z, agi[rr][n]);
                agi[rr][n] = fmaf(mv[n].w, wi.w, agi[rr][n]);
                agh[rr][n] = fmaf(hv[n].x, wh.x, agh[rr][n]);
                agh[rr][n] = fmaf(hv[n].y, wh.y, agh[rr][n]);
                agh[rr][n] = fmaf(hv[n].z, wh.z, agh[rr][n]);
                agh[rr][n] = fmaf(hv[n].w, wh.w, agh[rr][n]);
            }
        }
    }
    #pragma unroll
    for (int rr = 0; rr < 3; ++rr)
        #pragma unroll
        for (int n = 0; n < 8; ++n) {
            sgi[n * 384 + r + rr * 128] = agi[rr][n];
            sgh[n * 384 + r + rr * 128] = agh[rr][n];
        }
    __syncthreads();

    for (int idx = t; idx < 8 * 128; idx += 128) {
        int n = idx >> 7, j = idx & 127;
        if (n0 + n >= N) continue;
        float ir = sgi[n * 384 + j],        hr = sgh[n * 384 + j];
        float iz = sgi[n * 384 + 128 + j],  hz = sgh[n * 384 + 128 + j];
        float in_ = sgi[n * 384 + 256 + j], hn = sgh[n * 384 + 256 + j];
        float rg = 1.0f / (1.0f + expf(-(ir + hr)));
        float zg = 1.0f / (1.0f + expf(-(iz + hz)));
        float ng = tanhf(in_ + rg * hn);
        float hp = sh[n * 132 + j];
        float hnew = (1.0f - zg) * ng + zg * hp;
        newmem[(n0 + n) * 128 + j] = (scnt[n] > 0.0f) ? hnew : hp;
    }
}

// ------------------------- Kernel C: embeddings + dot ----------------------
// block = 128 threads, tile = 32 edges, both sides (src/dst) in one block.
// c = [new_mem(128) | feats(64)] (192); LDS 2*32 rows x 196; h reuses (stride 68).
__global__ __launch_bounds__(128) void k_embed(
    const int* __restrict__ src, const int* __restrict__ dst,
    const float* __restrict__ sf, const float* __restrict__ df,
    const float* __restrict__ newmem,
    const float* __restrict__ w1, const float* __restrict__ b1,
    const float* __restrict__ w2, const float* __restrict__ b2,
    float* __restrict__ out, int E)
{
    __shared__ float cs[2 * 32 * 196];
    const int t  = threadIdx.x;
    const int e0 = blockIdx.x * 32;

    for (int idx = t; idx < 2 * 32 * 192; idx += 128) {
        int side = idx / (32 * 192);
        int rem  = idx - side * (32 * 192);
        int e = rem / 192;
        int k = rem - e * 192;
        int ge = e0 + e;
        float v = 0.0f;
        if (ge < E) {
            int id = side ? dst[ge] : src[ge];
            if (k < 128) v = newmem[id * 128 + k];
            else         v = (side ? df : sf)[ge * 64 + (k - 128)];
        }
        cs[(side * 32 + e) * 196 + k] = v;
    }
    __syncthreads();

    const int j0   = (t & 7) * 8;      // 8 groups cover 64 output cols
    const int g    = t >> 3;           // 16 groups: side x 8 edge-blocks
    const int side = g & 1;
    const int eb   = (g >> 1) * 4;
    const int row0 = side * 32 + eb;

    // GEMM1: h = relu(c @ w1 + b1), K=192
    float acc[4][8];
    #pragma unroll
    for (int j = 0; j < 8; ++j) {
        float b = b1[j0 + j];
        #pragma unroll
        for (int i = 0; i < 4; ++i) acc[i][j] = b;
    }
    for (int k = 0; k < 192; k += 4) {
        float4 cv[4];
        #pragma unroll
        for (int i = 0; i < 4; ++i) cv[i] = *(const float4*)&cs[(row0 + i) * 196 + k];
        #pragma unroll
        for (int kk = 0; kk < 4; ++kk) {
            const float4 wa = *(const float4*)&w1[(k + kk) * 64 + j0];
            const float4 wb = *(const float4*)&w1[(k + kk) * 64 + j0 + 4];
            #pragma unroll
            for (int i = 0; i < 4; ++i) {
                const float x = ((const float*)&cv[i])[kk];
                acc[i][0] = fmaf(x, wa.x, acc[i][0]);
                acc[i][1] = fmaf(x, wa.y, acc[i][1]);
                acc[i][2] = fmaf(x, wa.z, acc[i][2]);
                acc[i][3] = fmaf(x, wa.w, acc[i][3]);
                acc[i][4] = fmaf(x, wb.x, acc[i][4]);
                acc[i][5] = fmaf(x, wb.y, acc[i][5]);
                acc[i][6] = fmaf(x, wb.z, acc[i][6]);
                acc[i][7] = fmaf(x, wb.w, acc[i][7]);
            }
        }
    }
    __syncthreads();   // reuse cs for h (stride 68)
    #pragma unroll
    for (int i = 0; i < 4; ++i)
        #pragma unroll
        for (int j = 0; j < 8; ++j)
            cs[(row0 + i) * 68 + (j0 + j)] = fmaxf(acc[i][j], 0.0f);
    __syncthreads();

    // GEMM2: emb = h @ w2 + b2, K=64
    float acc2[4][8];
    #pragma unroll
    for (int j = 0; j < 8; ++j) {
        float b = b2[j0 + j];
        #pragma unroll
        for (int i = 0; i < 4; ++i) acc2[i][j] = b;
    }
    for (int k = 0; k < 64; k += 4) {
        float4 hv[4];
        #pragma unroll
        for (int i = 0; i < 4; ++i) hv[i] = *(const float4*)&cs[(row0 + i) * 68 + k];
        #pragma unroll
        for (int kk = 0; kk < 4; ++kk) {
            const float4 wa = *(const float4*)&w2[(k + kk) * 64 + j0];
            const float4 wb = *(const float4*)&w2[(k + kk) * 64 + j0 + 4];
            #pragma unroll
            for (int i = 0; i < 4; ++i) {
                const float h = ((const float*)&hv[i])[kk];
                acc2[i][0] = fmaf(h, wa.x, acc2[i][0]);
                acc2[i][1] = fmaf(h, wa.y, acc2[i][1]);
                acc2[i][2] = fmaf(h, wa.z, acc2[i][2]);
                acc2[i][3] = fmaf(h, wa.w, acc2[i][3]);
                acc2[i][4] = fmaf(h, wb.x, acc2[i][4]);
                acc2[i][5] = fmaf(h, wb.y, acc2[i][5]);
                acc2[i][6] = fmaf(h, wb.z, acc2[i][6]);
                acc2[i][7] = fmaf(h, wb.w, acc2[i][7]);
            }
        }
    }

    // dot(src_emb, dst_emb): partner lane is t^8 (other side, same edge/cols)
    float p[4];
    #pragma unroll
    for (int i = 0; i < 4; ++i) {
        float s = 0.0f;
        #pragma unroll
        for (int j = 0; j < 8; ++j) {
            float mine  = acc2[i][j];
            float other = __shfl_xor(mine, 8, 64);
            s = fmaf(mine, other, s);
        }
        p[i] = s;
    }
    #pragma unroll
    for (int off = 4; off >= 1; off >>= 1) {
        #pragma unroll
        for (int i = 0; i < 4; ++i) p[i] += __shfl_down(p[i], off, 64);
    }
    if ((t & 15) == 0) {
        #pragma unroll
        for (int i = 0; i < 4; ++i) {
            int ge = e0 + eb + i;
            if (ge < E) out[ge] = p[i];
        }
    }
}

// ---------------------------------------------------------------------------
extern "C" void kernel_launch(void* const* d_in, const int* in_sizes, int n_in,
                              void* d_out, int out_size, void* d_ws, size_t ws_size,
                              hipStream_t stream)
{
    const int*   src = (const int*)d_in[0];
    const int*   dst = (const int*)d_in[1];
    const float* ef  = (const float*)d_in[2];
    const float* ts  = (const float*)d_in[3];
    const float* sf  = (const float*)d_in[4];
    const float* df  = (const float*)d_in[5];
    const float* mem = (const float*)d_in[6];
    const float* tw  = (const float*)d_in[7];
    const float* tb  = (const float*)d_in[8];
    const float* mw1 = (const float*)d_in[9];
    const float* mb1 = (const float*)d_in[10];
    const float* mw2 = (const float*)d_in[11];
    const float* mb2 = (const float*)d_in[12];
    const float* wih = (const float*)d_in[13];
    const float* whh = (const float*)d_in[14];
    const float* bih = (const float*)d_in[15];
    const float* bhh = (const float*)d_in[16];
    const float* ew1 = (const float*)d_in[17];
    const float* eb1 = (const float*)d_in[18];
    const float* ew2 = (const float*)d_in[19];
    const float* eb2 = (const float*)d_in[20];

    const int E = in_sizes[0];
    const int N = in_sizes[6] / 128;

    float* aggr   = (float*)d_ws;                    // N*128
    float* cnt    = aggr + (size_t)N * 128;          // N
    float* newmem = cnt + N;                         // N*128

    // zero aggr + counts (ws is poisoned before every call)
    hipMemsetAsync(d_ws, 0, (size_t)(N * 128 + N) * sizeof(float), stream);

    k_edge_msg<<<(E + 31) / 32, 128, 0, stream>>>(src, dst, ef, ts, mem, tw, tb,
                                                  mw1, mb1, mw2, mb2, aggr, cnt, E);
    k_gru<<<(N + 7) / 8, 128, 0, stream>>>(aggr, cnt, mem, wih, whh, bih, bhh, newmem, N);
    k_embed<<<(E + 31) / 32, 128, 0, stream>>>(src, dst, sf, df, newmem,
                                               ew1, eb1, ew2, eb2, (float*)d_out, E);
}

// Round 2
// 4045.590 us; speedup vs baseline: 1.7990x; 1.7990x over previous
//
#include <hip/hip_runtime.h>
#include <math.h>

// ---------------------------------------------------------------------------
// TGN forward v2: atomic-free aggregation via CSR gather.
//   k_hist  : int degree histogram
//   k_scan  : single-block chunked exclusive scan -> offs, cursor
//   k_fill  : edge-list fill via int atomic cursors
//   k_edge_msg : message MLP, writes bf16 msg rows (no float atomics)
//   k_gru   : CSR gather-mean + GRU memory update
//   k_embed : embedding MLPs + dot
// ---------------------------------------------------------------------------

static __device__ __forceinline__ unsigned short f2bf(float f) {
    unsigned int u = __float_as_uint(f);
    unsigned int r = (u + 0x7FFFu + ((u >> 16) & 1u)) >> 16;   // RNE
    return (unsigned short)r;
}
static __device__ __forceinline__ float bf2f(unsigned short v) {
    return __uint_as_float(((unsigned int)v) << 16);
}

// ------------------------- CSR build ---------------------------------------
__global__ __launch_bounds__(256) void k_hist(const int* __restrict__ src,
                                              const int* __restrict__ dst,
                                              int* __restrict__ deg, int E) {
    int e = blockIdx.x * 256 + threadIdx.x;
    if (e < E) {
        atomicAdd(&deg[src[e]], 1);
        atomicAdd(&deg[dst[e]], 1);
    }
}

__global__ __launch_bounds__(1024) void k_scan(const int* __restrict__ deg,
                                               int* __restrict__ offs,
                                               int* __restrict__ cursor, int N) {
    __shared__ int ssum[1024];
    const int t = threadIdx.x;
    const int chunk = (N + 1023) / 1024;
    const int lo = t * chunk;
    const int hi = min(lo + chunk, N);
    int s = 0;
    for (int i = lo; i < hi; ++i) s += deg[i];
    ssum[t] = s;
    __syncthreads();
    int inc = s;
    for (int off = 1; off < 1024; off <<= 1) {
        int u = (t >= off) ? ssum[t - off] : 0;
        __syncthreads();
        inc += u;
        ssum[t] = inc;
        __syncthreads();
    }
    int run = inc - s;  // exclusive prefix of chunk sums
    for (int i = lo; i < hi; ++i) {
        offs[i] = run;
        cursor[i] = run;
        run += deg[i];
    }
    if (lo < N && hi == N) offs[N] = run;
}

__global__ __launch_bounds__(256) void k_fill(const int* __restrict__ src,
                                              const int* __restrict__ dst,
                                              int* __restrict__ cursor,
                                              int* __restrict__ elist, int E) {
    int e = blockIdx.x * 256 + threadIdx.x;
    if (e < E) {
        int p = atomicAdd(&cursor[src[e]], 1);
        elist[p] = e;
        int q = atomicAdd(&cursor[dst[e]], 1);
        elist[q] = e;
    }
}

// ------------------------- Kernel A: edge messages -------------------------
// block = 128 threads, tile = 32 edges. Writes bf16 msg rows, no atomics.
__global__ __launch_bounds__(128) void k_edge_msg(
    const int* __restrict__ src, const int* __restrict__ dst,
    const float* __restrict__ ef, const float* __restrict__ ts,
    const float* __restrict__ mem, const float* __restrict__ tw, const float* __restrict__ tb,
    const float* __restrict__ w1, const float* __restrict__ b1,
    const float* __restrict__ w2, const float* __restrict__ b2,
    unsigned short* __restrict__ msg, int E)
{
    __shared__ float xs[32 * 324];
    __shared__ int eids[64];          // [0..31]=src, [32..63]=dst
    const int t  = threadIdx.x;
    const int e0 = blockIdx.x * 32;

    if (t < 64) {
        int e = t & 31, side = t >> 5;
        int ge = e0 + e;
        eids[t] = (ge < E) ? (side ? dst[ge] : src[ge]) : 0;
    }
    __syncthreads();

    // float4 staging of [src_mem(128) | dst_mem(128) | edge_feat(32)] = 72 q/row
    for (int idx = t; idx < 32 * 72; idx += 128) {
        int e = idx / 72;
        int q = idx - e * 72;
        int ge = e0 + e;
        float4 v = make_float4(0.f, 0.f, 0.f, 0.f);
        if (ge < E) {
            if (q < 32)      v = *(const float4*)&mem[(size_t)eids[e] * 128 + q * 4];
            else if (q < 64) v = *(const float4*)&mem[(size_t)eids[32 + e] * 128 + (q - 32) * 4];
            else             v = *(const float4*)&ef[(size_t)ge * 32 + (q - 64) * 4];
        }
        *(float4*)&xs[e * 324 + q * 4] = v;
    }
    // time encoding: cols 288..319
    for (int idx = t; idx < 32 * 32; idx += 128) {
        int e = idx >> 5, q = idx & 31;
        int ge = e0 + e;
        float v = 0.0f;
        if (ge < E) v = cosf(ts[ge] * tw[q] + tb[q]);
        xs[e * 324 + 288 + q] = v;
    }
    __syncthreads();

    const int j0 = (t & 15) * 8;     // 16 groups cover 128 output cols
    const int eb = (t >> 4) * 4;     // 8 groups x 4 edges

    // GEMM1: h1 = relu(x @ w1 + b1), K=320
    float acc[4][8];
    #pragma unroll
    for (int j = 0; j < 8; ++j) {
        float b = b1[j0 + j];
        #pragma unroll
        for (int i = 0; i < 4; ++i) acc[i][j] = b;
    }
    for (int k = 0; k < 320; k += 4) {
        float4 xv[4];
        #pragma unroll
        for (int i = 0; i < 4; ++i) xv[i] = *(const float4*)&xs[(eb + i) * 324 + k];
        #pragma unroll
        for (int kk = 0; kk < 4; ++kk) {
            const float4 wa = *(const float4*)&w1[(k + kk) * 128 + j0];
            const float4 wb = *(const float4*)&w1[(k + kk) * 128 + j0 + 4];
            #pragma unroll
            for (int i = 0; i < 4; ++i) {
                const float x = ((const float*)&xv[i])[kk];
                acc[i][0] = fmaf(x, wa.x, acc[i][0]);
                acc[i][1] = fmaf(x, wa.y, acc[i][1]);
                acc[i][2] = fmaf(x, wa.z, acc[i][2]);
                acc[i][3] = fmaf(x, wa.w, acc[i][3]);
                acc[i][4] = fmaf(x, wb.x, acc[i][4]);
                acc[i][5] = fmaf(x, wb.y, acc[i][5]);
                acc[i][6] = fmaf(x, wb.z, acc[i][6]);
                acc[i][7] = fmaf(x, wb.w, acc[i][7]);
            }
        }
    }
    __syncthreads();   // reuse xs for h1 (stride 132)
    #pragma unroll
    for (int i = 0; i < 4; ++i)
        #pragma unroll
        for (int j = 0; j < 8; ++j)
            xs[(eb + i) * 132 + (j0 + j)] = fmaxf(acc[i][j], 0.0f);
    __syncthreads();

    // GEMM2: msg = h1 @ w2 + b2, K=128
    float acc2[4][8];
    #pragma unroll
    for (int j = 0; j < 8; ++j) {
        float b = b2[j0 + j];
        #pragma unroll
        for (int i = 0; i < 4; ++i) acc2[i][j] = b;
    }
    for (int k = 0; k < 128; k += 4) {
        float4 hv[4];
        #pragma unroll
        for (int i = 0; i < 4; ++i) hv[i] = *(const float4*)&xs[(eb + i) * 132 + k];
        #pragma unroll
        for (int kk = 0; kk < 4; ++kk) {
            const float4 wa = *(const float4*)&w2[(k + kk) * 128 + j0];
            const float4 wb = *(const float4*)&w2[(k + kk) * 128 + j0 + 4];
            #pragma unroll
            for (int i = 0; i < 4; ++i) {
                const float h = ((const float*)&hv[i])[kk];
                acc2[i][0] = fmaf(h, wa.x, acc2[i][0]);
                acc2[i][1] = fmaf(h, wa.y, acc2[i][1]);
                acc2[i][2] = fmaf(h, wa.z, acc2[i][2]);
                acc2[i][3] = fmaf(h, wa.w, acc2[i][3]);
                acc2[i][4] = fmaf(h, wb.x, acc2[i][4]);
                acc2[i][5] = fmaf(h, wb.y, acc2[i][5]);
                acc2[i][6] = fmaf(h, wb.z, acc2[i][6]);
                acc2[i][7] = fmaf(h, wb.w, acc2[i][7]);
            }
        }
    }

    // write bf16 msg rows: 8 cols (16 B) per edge per thread-group
    #pragma unroll
    for (int i = 0; i < 4; ++i) {
        int ge = e0 + eb + i;
        if (ge < E) {
            uint4 p;
            p.x = ((unsigned)f2bf(acc2[i][1]) << 16) | f2bf(acc2[i][0]);
            p.y = ((unsigned)f2bf(acc2[i][3]) << 16) | f2bf(acc2[i][2]);
            p.z = ((unsigned)f2bf(acc2[i][5]) << 16) | f2bf(acc2[i][4]);
            p.w = ((unsigned)f2bf(acc2[i][7]) << 16) | f2bf(acc2[i][6]);
            *(uint4*)&msg[(size_t)ge * 128 + j0] = p;
        }
    }
}

// ------------------------- Kernel B: gather + GRU --------------------------
// block = 128 threads, tile = 8 nodes. Thread t = column t for the gather,
// then output rows t, t+128, t+256 for the matvecs.
__global__ __launch_bounds__(128) void k_gru(
    const unsigned short* __restrict__ msg, const int* __restrict__ offs,
    const int* __restrict__ elist, const int* __restrict__ deg,
    const float* __restrict__ mem,
    const float* __restrict__ wih, const float* __restrict__ whh,
    const float* __restrict__ bih, const float* __restrict__ bhh,
    float* __restrict__ newmem, int N)
{
    __shared__ float sm[8 * 132];
    __shared__ float sh[8 * 132];
    __shared__ float sgi[8 * 384];
    __shared__ float sgh[8 * 384];
    __shared__ int sdeg[8];
    const int t  = threadIdx.x;
    const int n0 = blockIdx.x * 8;

    if (t < 8) sdeg[t] = (n0 + t < N) ? deg[n0 + t] : 0;

    // gather-mean: thread t owns column t
    for (int n = 0; n < 8; ++n) {
        int node = n0 + n;
        float s = 0.0f, h = 0.0f;
        if (node < N) {
            int a = offs[node], b = offs[node + 1];
            for (int i = a; i < b; ++i) {
                int e = elist[i];
                s += bf2f(msg[(size_t)e * 128 + t]);
            }
            int d = b - a;
            if (d > 0) s /= (float)d;
            h = mem[(size_t)node * 128 + t];
        }
        sm[n * 132 + t] = s;
        sh[n * 132 + t] = h;
    }
    __syncthreads();

    const int r = t;
    float agi[3][8], agh[3][8];
    #pragma unroll
    for (int rr = 0; rr < 3; ++rr) {
        float bi = bih[r + rr * 128];
        float bh = bhh[r + rr * 128];
        #pragma unroll
        for (int n = 0; n < 8; ++n) { agi[rr][n] = bi; agh[rr][n] = bh; }
    }
    for (int k = 0; k < 128; k += 4) {
        float4 mv[8], hv[8];
        #pragma unroll
        for (int n = 0; n < 8; ++n) {
            mv[n] = *(const float4*)&sm[n * 132 + k];
            hv[n] = *(const float4*)&sh[n * 132 + k];
        }
        #pragma unroll
        for (int rr = 0; rr < 3; ++rr) {
            const float4 wi = *(const float4*)&wih[(size_t)(r + rr * 128) * 128 + k];
            const float4 wh = *(const float4*)&whh[(size_t)(r + rr * 128) * 128 + k];
            #pragma unroll
            for (int n = 0; n < 8; ++n) {
                agi[rr][n] = fmaf(mv[n].x, wi.x, agi[rr][n]);
                agi[rr][n] = fmaf(mv[n].y, wi.y, agi[rr][n]);
                agi[rr][n] = fmaf(mv[n].z, wi.z, agi[rr][n]);
                agi[rr][n] = fmaf(mv[n].w, wi.w, agi[rr][n]);
                agh[rr][n] = fmaf(hv[n].x, wh.x, agh[rr][n]);
                agh[rr][n] = fmaf(hv[n].y, wh.y, agh[rr][n]);
                agh[rr][n] = fmaf(hv[n].z, wh.z, agh[rr][n]);
                agh[rr][n] = fmaf(hv[n].w, wh.w, agh[rr][n]);
            }
        }
    }
    #pragma unroll
    for (int rr = 0; rr < 3; ++rr)
        #pragma unroll
        for (int n = 0; n < 8; ++n) {
            sgi[n * 384 + r + rr * 128] = agi[rr][n];
            sgh[n * 384 + r + rr * 128] = agh[rr][n];
        }
    __syncthreads();

    for (int idx = t; idx < 8 * 128; idx += 128) {
        int n = idx >> 7, j = idx & 127;
        if (n0 + n >= N) continue;
        float ir = sgi[n * 384 + j],        hr = sgh[n * 384 + j];
        float iz = sgi[n * 384 + 128 + j],  hz = sgh[n * 384 + 128 + j];
        float in_ = sgi[n * 384 + 256 + j], hn = sgh[n * 384 + 256 + j];
        float rg = 1.0f / (1.0f + expf(-(ir + hr)));
        float zg = 1.0f / (1.0f + expf(-(iz + hz)));
        float ng = tanhf(in_ + rg * hn);
        float hp = sh[n * 132 + j];
        float hnew = (1.0f - zg) * ng + zg * hp;
        newmem[(size_t)(n0 + n) * 128 + j] = (sdeg[n] > 0) ? hnew : hp;
    }
}

// ------------------------- Kernel C: embeddings + dot ----------------------
__global__ __launch_bounds__(128) void k_embed(
    const int* __restrict__ src, const int* __restrict__ dst,
    const float* __restrict__ sf, const float* __restrict__ df,
    const float* __restrict__ newmem,
    const float* __restrict__ w1, const float* __restrict__ b1,
    const float* __restrict__ w2, const float* __restrict__ b2,
    float* __restrict__ out, int E)
{
    __shared__ float cs[2 * 32 * 196];
    __shared__ int ids[64];
    const int t  = threadIdx.x;
    const int e0 = blockIdx.x * 32;

    if (t < 64) {
        int e = t & 31, side = t >> 5;
        int ge = e0 + e;
        ids[t] = (ge < E) ? (side ? dst[ge] : src[ge]) : 0;
    }
    __syncthreads();

    // float4 staging: c = [new_mem(32 q) | feats(16 q)] = 48 q per row
    for (int idx = t; idx < 2 * 32 * 48; idx += 128) {
        int side = idx / (32 * 48);
        int rem  = idx - side * (32 * 48);
        int e = rem / 48;
        int q = rem - e * 48;
        int ge = e0 + e;
        float4 v = make_float4(0.f, 0.f, 0.f, 0.f);
        if (ge < E) {
            if (q < 32) v = *(const float4*)&newmem[(size_t)ids[side * 32 + e] * 128 + q * 4];
            else        v = *(const float4*)&(side ? df : sf)[(size_t)ge * 64 + (q - 32) * 4];
        }
        *(float4*)&cs[(side * 32 + e) * 196 + q * 4] = v;
    }
    __syncthreads();

    const int j0   = (t & 7) * 8;      // 8 groups cover 64 output cols
    const int g    = t >> 3;           // 16 groups: side x 8 edge-blocks
    const int side = g & 1;
    const int eb   = (g >> 1) * 4;
    const int row0 = side * 32 + eb;

    // GEMM1: h = relu(c @ w1 + b1), K=192
    float acc[4][8];
    #pragma unroll
    for (int j = 0; j < 8; ++j) {
        float b = b1[j0 + j];
        #pragma unroll
        for (int i = 0; i < 4; ++i) acc[i][j] = b;
    }
    for (int k = 0; k < 192; k += 4) {
        float4 cv[4];
        #pragma unroll
        for (int i = 0; i < 4; ++i) cv[i] = *(const float4*)&cs[(row0 + i) * 196 + k];
        #pragma unroll
        for (int kk = 0; kk < 4; ++kk) {
            const float4 wa = *(const float4*)&w1[(k + kk) * 64 + j0];
            const float4 wb = *(const float4*)&w1[(k + kk) * 64 + j0 + 4];
            #pragma unroll
            for (int i = 0; i < 4; ++i) {
                const float x = ((const float*)&cv[i])[kk];
                acc[i][0] = fmaf(x, wa.x, acc[i][0]);
                acc[i][1] = fmaf(x, wa.y, acc[i][1]);
                acc[i][2] = fmaf(x, wa.z, acc[i][2]);
                acc[i][3] = fmaf(x, wa.w, acc[i][3]);
                acc[i][4] = fmaf(x, wb.x, acc[i][4]);
                acc[i][5] = fmaf(x, wb.y, acc[i][5]);
                acc[i][6] = fmaf(x, wb.z, acc[i][6]);
                acc[i][7] = fmaf(x, wb.w, acc[i][7]);
            }
        }
    }
    __syncthreads();   // reuse cs for h (stride 68)
    #pragma unroll
    for (int i = 0; i < 4; ++i)
        #pragma unroll
        for (int j = 0; j < 8; ++j)
            cs[(row0 + i) * 68 + (j0 + j)] = fmaxf(acc[i][j], 0.0f);
    __syncthreads();

    // GEMM2: emb = h @ w2 + b2, K=64
    float acc2[4][8];
    #pragma unroll
    for (int j = 0; j < 8; ++j) {
        float b = b2[j0 + j];
        #pragma unroll
        for (int i = 0; i < 4; ++i) acc2[i][j] = b;
    }
    for (int k = 0; k < 64; k += 4) {
        float4 hv[4];
        #pragma unroll
        for (int i = 0; i < 4; ++i) hv[i] = *(const float4*)&cs[(row0 + i) * 68 + k];
        #pragma unroll
        for (int kk = 0; kk < 4; ++kk) {
            const float4 wa = *(const float4*)&w2[(k + kk) * 64 + j0];
            const float4 wb = *(const float4*)&w2[(k + kk) * 64 + j0 + 4];
            #pragma unroll
            for (int i = 0; i < 4; ++i) {
                const float h = ((const float*)&hv[i])[kk];
                acc2[i][0] = fmaf(h, wa.x, acc2[i][0]);
                acc2[i][1] = fmaf(h, wa.y, acc2[i][1]);
                acc2[i][2] = fmaf(h, wa.z, acc2[i][2]);
                acc2[i][3] = fmaf(h, wa.w, acc2[i][3]);
                acc2[i][4] = fmaf(h, wb.x, acc2[i][4]);
                acc2[i][5] = fmaf(h, wb.y, acc2[i][5]);
                acc2[i][6] = fmaf(h, wb.z, acc2[i][6]);
                acc2[i][7] = fmaf(h, wb.w, acc2[i][7]);
            }
        }
    }

    // dot(src_emb, dst_emb): partner lane is t^8 (other side, same edge/cols)
    float p[4];
    #pragma unroll
    for (int i = 0; i < 4; ++i) {
        float s = 0.0f;
        #pragma unroll
        for (int j = 0; j < 8; ++j) {
            float mine  = acc2[i][j];
            float other = __shfl_xor(mine, 8, 64);
            s = fmaf(mine, other, s);
        }
        p[i] = s;
    }
    #pragma unroll
    for (int off = 4; off >= 1; off >>= 1) {
        #pragma unroll
        for (int i = 0; i < 4; ++i) p[i] += __shfl_down(p[i], off, 64);
    }
    if ((t & 15) == 0) {
        #pragma unroll
        for (int i = 0; i < 4; ++i) {
            int ge = e0 + eb + i;
            if (ge < E) out[ge] = p[i];
        }
    }
}

// ---------------------------------------------------------------------------
extern "C" void kernel_launch(void* const* d_in, const int* in_sizes, int n_in,
                              void* d_out, int out_size, void* d_ws, size_t ws_size,
                              hipStream_t stream)
{
    const int*   src = (const int*)d_in[0];
    const int*   dst = (const int*)d_in[1];
    const float* ef  = (const float*)d_in[2];
    const float* ts  = (const float*)d_in[3];
    const float* sf  = (const float*)d_in[4];
    const float* df  = (const float*)d_in[5];
    const float* mem = (const float*)d_in[6];
    const float* tw  = (const float*)d_in[7];
    const float* tb  = (const float*)d_in[8];
    const float* mw1 = (const float*)d_in[9];
    const float* mb1 = (const float*)d_in[10];
    const float* mw2 = (const float*)d_in[11];
    const float* mb2 = (const float*)d_in[12];
    const float* wih = (const float*)d_in[13];
    const float* whh = (const float*)d_in[14];
    const float* bih = (const float*)d_in[15];
    const float* bhh = (const float*)d_in[16];
    const float* ew1 = (const float*)d_in[17];
    const float* eb1 = (const float*)d_in[18];
    const float* ew2 = (const float*)d_in[19];
    const float* eb2 = (const float*)d_in[20];

    const int E = in_sizes[0];
    const int N = in_sizes[6] / 128;

    // workspace carve-up (256B aligned chunks)
    size_t off = 0;
    auto carve = [&](size_t bytes) {
        size_t cur = off;
        off = (off + bytes + 255) & ~(size_t)255;
        return cur;
    };
    char* w = (char*)d_ws;
    int*            deg    = (int*)(w + carve((size_t)N * 4));
    int*            offs   = (int*)(w + carve((size_t)(N + 1) * 4));
    int*            cursor = (int*)(w + carve((size_t)N * 4));
    int*            elist  = (int*)(w + carve((size_t)2 * E * 4));
    float*          newmem = (float*)(w + carve((size_t)N * 128 * 4));
    unsigned short* msg    = (unsigned short*)(w + carve((size_t)E * 128 * 2));

    hipMemsetAsync(deg, 0, (size_t)N * 4, stream);

    k_hist<<<(E + 255) / 256, 256, 0, stream>>>(src, dst, deg, E);
    k_scan<<<1, 1024, 0, stream>>>(deg, offs, cursor, N);
    k_fill<<<(E + 255) / 256, 256, 0, stream>>>(src, dst, cursor, elist, E);
    k_edge_msg<<<(E + 31) / 32, 128, 0, stream>>>(src, dst, ef, ts, mem, tw, tb,
                                                  mw1, mb1, mw2, mb2, msg, E);
    k_gru<<<(N + 7) / 8, 128, 0, stream>>>(msg, offs, elist, deg, mem,
                                           wih, whh, bih, bhh, newmem, N);
    k_embed<<<(E + 31) / 32, 128, 0, stream>>>(src, dst, sf, df, newmem,
                                               ew1, eb1, ew2, eb2, (float*)d_out, E);
}

// Round 3
// 1076.129 us; speedup vs baseline: 6.7630x; 3.7594x over previous
//
#include <hip/hip_runtime.h>
#include <math.h>

// ---------------------------------------------------------------------------
// TGN forward v3: bf16 MFMA everywhere.
//   k_hist/k_scan/k_fill : CSR build (deg doubles as fill cursor)
//   k_cvt   : memory fp32 -> bf16 rows
//   k_pack  : pre-swizzle all weights into MFMA B-fragment layout (uint4/lane)
//   k_edge_msg : message MLP via MFMA, bf16 msg out
//   k_gru   : CSR gather-mean + GRU via MFMA, bf16 newmem out
//   k_embed : embedding MLPs via MFMA + dot
// MFMA 16x16x32 bf16 layouts (HW-verified): A[m=l&15][k=(l>>4)*8+j],
// B[k=(l>>4)*8+j][n=l&15], D[m=(l>>4)*4+reg][n=l&15].
// ---------------------------------------------------------------------------

typedef __attribute__((ext_vector_type(8))) short bf16x8;
typedef __attribute__((ext_vector_type(4))) float f32x4;

static __device__ __forceinline__ unsigned short f2bf(float f) {
    unsigned int u = __float_as_uint(f);
    unsigned int r = (u + 0x7FFFu + ((u >> 16) & 1u)) >> 16;   // RNE
    return (unsigned short)r;
}
static __device__ __forceinline__ float bf2f(unsigned int v) {
    return __uint_as_float(v << 16);
}
static __device__ __forceinline__ bf16x8 as_bf(uint4 u) {
    union { uint4 u; bf16x8 v; } c; c.u = u; return c.v;
}
static __device__ __forceinline__ bf16x8 cvt8(float4 a, float4 b) {
    bf16x8 r;
    r[0]=(short)f2bf(a.x); r[1]=(short)f2bf(a.y); r[2]=(short)f2bf(a.z); r[3]=(short)f2bf(a.w);
    r[4]=(short)f2bf(b.x); r[5]=(short)f2bf(b.y); r[6]=(short)f2bf(b.z); r[7]=(short)f2bf(b.w);
    return r;
}
// 8-byte-aligned LDS load of 8 bf16 (row strides are odd multiples of 8 B)
static __device__ __forceinline__ bf16x8 lds8(const unsigned short* p) {
    union { uint2 h[2]; bf16x8 v; } c;
    c.h[0] = *(const uint2*)p;
    c.h[1] = *(const uint2*)(p + 4);
    return c.v;
}
static __device__ __forceinline__ f32x4 mfma16(bf16x8 a, bf16x8 b, f32x4 c) {
    return __builtin_amdgcn_mfma_f32_16x16x32_bf16(a, b, c, 0, 0, 0);
}
static __device__ __forceinline__ f32x4 splat4(float v) {
    f32x4 c; c[0]=v; c[1]=v; c[2]=v; c[3]=v; return c;
}
static __device__ __forceinline__ float sigm(float x) {
    return 1.0f / (1.0f + expf(-x));
}

// ------------------------- CSR build ---------------------------------------
__global__ __launch_bounds__(256) void k_hist(const int* __restrict__ src,
                                              const int* __restrict__ dst,
                                              int* __restrict__ deg, int E) {
    int e = blockIdx.x * 256 + threadIdx.x;
    if (e < E) {
        atomicAdd(&deg[src[e]], 1);
        atomicAdd(&deg[dst[e]], 1);
    }
}

// writes offs[0..N]; overwrites deg[] with the running cursor (= offs[i])
__global__ __launch_bounds__(1024) void k_scan(int* __restrict__ deg,
                                               int* __restrict__ offs, int N) {
    __shared__ int ssum[1024];
    const int t = threadIdx.x;
    const int chunk = (N + 1023) / 1024;
    const int lo = t * chunk;
    const int hi = min(lo + chunk, N);
    int s = 0;
    for (int i = lo; i < hi; ++i) s += deg[i];
    ssum[t] = s;
    __syncthreads();
    int inc = s;
    for (int off = 1; off < 1024; off <<= 1) {
        int u = (t >= off) ? ssum[t - off] : 0;
        __syncthreads();
        inc += u;
        ssum[t] = inc;
        __syncthreads();
    }
    int run = inc - s;
    for (int i = lo; i < hi; ++i) {
        int d = deg[i];
        offs[i] = run;
        deg[i] = run;   // cursor
        run += d;
    }
    if (lo < N && hi == N) offs[N] = run;
}

__global__ __launch_bounds__(256) void k_fill(const int* __restrict__ src,
                                              const int* __restrict__ dst,
                                              int* __restrict__ cursor,
                                              int* __restrict__ elist, int E) {
    int e = blockIdx.x * 256 + threadIdx.x;
    if (e < E) {
        int p = atomicAdd(&cursor[src[e]], 1);
        elist[p] = e;
        int q = atomicAdd(&cursor[dst[e]], 1);
        elist[q] = e;
    }
}

// ------------------------- fp32 -> bf16 ------------------------------------
__global__ __launch_bounds__(256) void k_cvt(const float* __restrict__ x,
                                             unsigned short* __restrict__ y, int n) {
    int i = (blockIdx.x * 256 + threadIdx.x) * 8;
    if (i < n) {
        float4 a = *(const float4*)&x[i];
        float4 b = *(const float4*)&x[i + 4];
        *(bf16x8*)&y[i] = cvt8(a, b);
    }
}

// ------------------------- weight pre-swizzle ------------------------------
// frag f, lane l -> 8 bf16 of B[k=kstep*32+(l>>4)*8+j][n=ntile*16+(l&15)].
// frag ranges: w1p 0..79 | w2p 80..111 | wihp 112..207 | whhp 208..303 |
//              ew1p 304..327 | ew2p 328..335
__global__ __launch_bounds__(64) void k_pack(
    const float* __restrict__ w1, const float* __restrict__ w2,
    const float* __restrict__ wih, const float* __restrict__ whh,
    const float* __restrict__ ew1, const float* __restrict__ ew2,
    uint4* __restrict__ out)
{
    int f = blockIdx.x, l = threadIdx.x;
    const float* srcp; int NT, sk, sn, base;
    if (f < 80)       { srcp = w1;  NT = 8;  sk = 128; sn = 1;   base = 0;   }
    else if (f < 112) { srcp = w2;  NT = 8;  sk = 128; sn = 1;   base = 80;  }
    else if (f < 208) { srcp = wih; NT = 24; sk = 1;   sn = 128; base = 112; }
    else if (f < 304) { srcp = whh; NT = 24; sk = 1;   sn = 128; base = 208; }
    else if (f < 328) { srcp = ew1; NT = 4;  sk = 64;  sn = 1;   base = 304; }
    else              { srcp = ew2; NT = 4;  sk = 64;  sn = 1;   base = 328; }
    int fl = f - base;
    int kstep = fl / NT, ntile = fl - kstep * NT;
    int n  = ntile * 16 + (l & 15);
    int k0 = kstep * 32 + (l >> 4) * 8;
    unsigned short h[8];
    #pragma unroll
    for (int j = 0; j < 8; ++j)
        h[j] = f2bf(srcp[(size_t)(k0 + j) * sk + (size_t)n * sn]);
    uint4 p;
    p.x = h[0] | ((unsigned)h[1] << 16);
    p.y = h[2] | ((unsigned)h[3] << 16);
    p.z = h[4] | ((unsigned)h[5] << 16);
    p.w = h[6] | ((unsigned)h[7] << 16);
    out[(size_t)f * 64 + l] = p;
}

// ------------------------- Kernel A: edge messages -------------------------
// 256 threads = 4 waves; wave handles 32 edges (2 MFMA row-tiles).
__global__ __launch_bounds__(256) void k_edge_msg(
    const int* __restrict__ src, const int* __restrict__ dst,
    const float* __restrict__ ef, const float* __restrict__ ts,
    const unsigned short* __restrict__ membf,
    const float* __restrict__ tw, const float* __restrict__ tb,
    const uint4* __restrict__ w1p, const float* __restrict__ b1,
    const uint4* __restrict__ w2p, const float* __restrict__ b2,
    unsigned short* __restrict__ msg, int E)
{
    __shared__ unsigned short h1s[4 * 32 * 132];
    const int tid = threadIdx.x;
    const int wv = tid >> 6, l = tid & 63;
    const int li = l & 15, q = l >> 4;
    const long long e0 = (long long)blockIdx.x * 128 + wv * 32;

    long long eA = e0 + li;       if (eA > E - 1) eA = E - 1;
    long long eB = e0 + 16 + li;  if (eB > E - 1) eB = E - 1;
    const int sA = src[eA], sB = src[eB], dA = dst[eA], dB = dst[eB];
    const float tsA = ts[eA], tsB = ts[eB];

    // ---- GEMM1: h1 = relu(x @ w1 + b1), M=32, N=128, K=320 ----
    f32x4 acc[2][8];
    #pragma unroll
    for (int nt = 0; nt < 8; ++nt) {
        float bb = b1[nt * 16 + li];
        acc[0][nt] = splat4(bb);
        acc[1][nt] = splat4(bb);
    }
    #pragma unroll
    for (int ks = 0; ks < 10; ++ks) {
        bf16x8 a0, a1;
        if (ks < 4) {
            a0 = *(const bf16x8*)(membf + (size_t)sA * 128 + ks * 32 + q * 8);
            a1 = *(const bf16x8*)(membf + (size_t)sB * 128 + ks * 32 + q * 8);
        } else if (ks < 8) {
            a0 = *(const bf16x8*)(membf + (size_t)dA * 128 + (ks - 4) * 32 + q * 8);
            a1 = *(const bf16x8*)(membf + (size_t)dB * 128 + (ks - 4) * 32 + q * 8);
        } else if (ks == 8) {
            const float* pA = ef + (size_t)eA * 32 + q * 8;
            const float* pB = ef + (size_t)eB * 32 + q * 8;
            a0 = cvt8(*(const float4*)pA, *(const float4*)(pA + 4));
            a1 = cvt8(*(const float4*)pB, *(const float4*)(pB + 4));
        } else {
            float4 twa = *(const float4*)&tw[q * 8];
            float4 twb = *(const float4*)&tw[q * 8 + 4];
            float4 tba = *(const float4*)&tb[q * 8];
            float4 tbb = *(const float4*)&tb[q * 8 + 4];
            float4 cA0, cA1, cB0, cB1;
            cA0.x = cosf(tsA*twa.x+tba.x); cA0.y = cosf(tsA*twa.y+tba.y);
            cA0.z = cosf(tsA*twa.z+tba.z); cA0.w = cosf(tsA*twa.w+tba.w);
            cA1.x = cosf(tsA*twb.x+tbb.x); cA1.y = cosf(tsA*twb.y+tbb.y);
            cA1.z = cosf(tsA*twb.z+tbb.z); cA1.w = cosf(tsA*twb.w+tbb.w);
            cB0.x = cosf(tsB*twa.x+tba.x); cB0.y = cosf(tsB*twa.y+tba.y);
            cB0.z = cosf(tsB*twa.z+tba.z); cB0.w = cosf(tsB*twa.w+tba.w);
            cB1.x = cosf(tsB*twb.x+tbb.x); cB1.y = cosf(tsB*twb.y+tbb.y);
            cB1.z = cosf(tsB*twb.z+tbb.z); cB1.w = cosf(tsB*twb.w+tbb.w);
            a0 = cvt8(cA0, cA1);
            a1 = cvt8(cB0, cB1);
        }
        #pragma unroll
        for (int nt = 0; nt < 8; ++nt) {
            bf16x8 b = as_bf(w1p[(size_t)(ks * 8 + nt) * 64 + l]);
            acc[0][nt] = mfma16(a0, b, acc[0][nt]);
            acc[1][nt] = mfma16(a1, b, acc[1][nt]);
        }
    }

    // relu -> wave-private LDS (C layout -> row-major [32][132])
    unsigned short* hw = h1s + wv * 32 * 132;
    #pragma unroll
    for (int rt = 0; rt < 2; ++rt)
        #pragma unroll
        for (int nt = 0; nt < 8; ++nt)
            #pragma unroll
            for (int r = 0; r < 4; ++r)
                hw[(rt * 16 + q * 4 + r) * 132 + nt * 16 + li] =
                    f2bf(fmaxf(acc[rt][nt][r], 0.0f));

    // ---- GEMM2: msg = h1 @ w2 + b2, K=128 ----
    f32x4 acc2[2][8];
    #pragma unroll
    for (int nt = 0; nt < 8; ++nt) {
        float bb = b2[nt * 16 + li];
        acc2[0][nt] = splat4(bb);
        acc2[1][nt] = splat4(bb);
    }
    #pragma unroll
    for (int ks = 0; ks < 4; ++ks) {
        bf16x8 a0 = lds8(hw + (li) * 132 + ks * 32 + q * 8);
        bf16x8 a1 = lds8(hw + (16 + li) * 132 + ks * 32 + q * 8);
        #pragma unroll
        for (int nt = 0; nt < 8; ++nt) {
            bf16x8 b = as_bf(w2p[(size_t)(ks * 8 + nt) * 64 + l]);
            acc2[0][nt] = mfma16(a0, b, acc2[0][nt]);
            acc2[1][nt] = mfma16(a1, b, acc2[1][nt]);
        }
    }

    // store bf16 msg rows
    #pragma unroll
    for (int rt = 0; rt < 2; ++rt)
        #pragma unroll
        for (int r = 0; r < 4; ++r) {
            long long ge = e0 + rt * 16 + q * 4 + r;
            if (ge < E) {
                #pragma unroll
                for (int nt = 0; nt < 8; ++nt)
                    msg[(size_t)ge * 128 + nt * 16 + li] = f2bf(acc2[rt][nt][r]);
            }
        }
}

// ------------------------- Kernel B: gather + GRU --------------------------
// 256 threads = 4 waves; block = 128 nodes; wave = 32 nodes (2 row-tiles).
__global__ __launch_bounds__(256) void k_gru(
    const unsigned short* __restrict__ msg, const int* __restrict__ offs,
    const int* __restrict__ elist,
    const unsigned short* __restrict__ membf, const float* __restrict__ memf,
    const uint4* __restrict__ wihp, const uint4* __restrict__ whhp,
    const float* __restrict__ bih, const float* __restrict__ bhh,
    unsigned short* __restrict__ nmbf, int N)
{
    __shared__ unsigned short means[128 * 132];
    const int tid = threadIdx.x;
    const int n0 = blockIdx.x * 128;

    // ---- gather-mean: 4 threads/node, 32 cols each, 2 node-reps ----
    #pragma unroll
    for (int rep = 0; rep < 2; ++rep) {
        int nl = (tid >> 2) + rep * 64;
        int part = tid & 3;
        int node = n0 + nl;
        float acc[32];
        #pragma unroll
        for (int c = 0; c < 32; ++c) acc[c] = 0.0f;
        int a = 0, b = 0;
        if (node < N) { a = offs[node]; b = offs[node + 1]; }
        for (int i = a; i < b; ++i) {
            int e = elist[i];
            const uint4* mr = (const uint4*)(msg + (size_t)e * 128 + part * 32);
            #pragma unroll
            for (int g = 0; g < 4; ++g) {
                uint4 u = mr[g];
                acc[g*8+0] += bf2f(u.x & 0xffffu); acc[g*8+1] += bf2f(u.x >> 16);
                acc[g*8+2] += bf2f(u.y & 0xffffu); acc[g*8+3] += bf2f(u.y >> 16);
                acc[g*8+4] += bf2f(u.z & 0xffffu); acc[g*8+5] += bf2f(u.z >> 16);
                acc[g*8+6] += bf2f(u.w & 0xffffu); acc[g*8+7] += bf2f(u.w >> 16);
            }
        }
        float inv = (b > a) ? 1.0f / (float)(b - a) : 0.0f;
        unsigned short* mp = means + nl * 132 + part * 32;
        #pragma unroll
        for (int g = 0; g < 8; ++g) {
            uint2 t2;
            t2.x = f2bf(acc[g*4+0]*inv) | ((unsigned)f2bf(acc[g*4+1]*inv) << 16);
            t2.y = f2bf(acc[g*4+2]*inv) | ((unsigned)f2bf(acc[g*4+3]*inv) << 16);
            *(uint2*)(mp + g * 4) = t2;
        }
    }
    __syncthreads();

    const int wv = tid >> 6, l = tid & 63;
    const int li = l & 15, q = l >> 4;
    const int nb = n0 + wv * 32;

    // A fragments (fixed across all gate tiles)
    bf16x8 meanA[2][4], memA[2][4];
    #pragma unroll
    for (int rt = 0; rt < 2; ++rt) {
        int rowl = wv * 32 + rt * 16 + li;
        int node = min(n0 + rowl, N - 1);
        #pragma unroll
        for (int ks = 0; ks < 4; ++ks) {
            meanA[rt][ks] = lds8(means + rowl * 132 + ks * 32 + q * 8);
            memA[rt][ks]  = *(const bf16x8*)(membf + (size_t)node * 128 + ks * 32 + q * 8);
        }
    }

    int degv[2][4];
    #pragma unroll
    for (int rt = 0; rt < 2; ++rt)
        #pragma unroll
        for (int r = 0; r < 4; ++r) {
            int node = min(nb + rt * 16 + q * 4 + r, N - 1);
            degv[rt][r] = offs[node + 1] - offs[node];
        }

    #pragma unroll
    for (int t = 0; t < 8; ++t) {
        f32x4 ai[2][3], ah[2][3];
        #pragma unroll
        for (int g = 0; g < 3; ++g) {
            float bi = bih[g * 128 + t * 16 + li];
            float bh = bhh[g * 128 + t * 16 + li];
            ai[0][g] = splat4(bi); ai[1][g] = splat4(bi);
            ah[0][g] = splat4(bh); ah[1][g] = splat4(bh);
        }
        #pragma unroll
        for (int ks = 0; ks < 4; ++ks) {
            #pragma unroll
            for (int g = 0; g < 3; ++g) {
                bf16x8 bi = as_bf(wihp[(size_t)(ks * 24 + t + g * 8) * 64 + l]);
                bf16x8 bh = as_bf(whhp[(size_t)(ks * 24 + t + g * 8) * 64 + l]);
                ai[0][g] = mfma16(meanA[0][ks], bi, ai[0][g]);
                ai[1][g] = mfma16(meanA[1][ks], bi, ai[1][g]);
                ah[0][g] = mfma16(memA[0][ks], bh, ah[0][g]);
                ah[1][g] = mfma16(memA[1][ks], bh, ah[1][g]);
            }
        }
        #pragma unroll
        for (int rt = 0; rt < 2; ++rt)
            #pragma unroll
            for (int r = 0; r < 4; ++r) {
                int node = nb + rt * 16 + q * 4 + r;
                int nc = min(node, N - 1);
                float hp = memf[(size_t)nc * 128 + t * 16 + li];
                float rg = sigm(ai[rt][0][r] + ah[rt][0][r]);
                float zg = sigm(ai[rt][1][r] + ah[rt][1][r]);
                float ng = tanhf(ai[rt][2][r] + rg * ah[rt][2][r]);
                float hnew = (degv[rt][r] > 0) ? (1.0f - zg) * ng + zg * hp : hp;
                if (node < N)
                    nmbf[(size_t)node * 128 + t * 16 + li] = f2bf(hnew);
            }
    }
}

// ------------------------- Kernel C: embeddings + dot ----------------------
// 256 threads = 4 waves; block = 64 edges; waves 0,1 = src rows, 2,3 = dst.
__global__ __launch_bounds__(256) void k_embed(
    const int* __restrict__ src, const int* __restrict__ dst,
    const float* __restrict__ sf, const float* __restrict__ df,
    const unsigned short* __restrict__ nmbf,
    const uint4* __restrict__ ew1p, const float* __restrict__ b1,
    const uint4* __restrict__ ew2p, const float* __restrict__ b2,
    float* __restrict__ out, int E)
{
    __shared__ float embs[128 * 68];
    __shared__ unsigned short hs[4 * 32 * 68];
    const int tid = threadIdx.x;
    const int wv = tid >> 6, l = tid & 63;
    const int li = l & 15, q = l >> 4;
    const long long e0 = (long long)blockIdx.x * 64;

    const int side = wv >> 1;
    long long eA = e0 + (wv & 1) * 32 + li;      if (eA > E - 1) eA = E - 1;
    long long eB = e0 + (wv & 1) * 32 + 16 + li; if (eB > E - 1) eB = E - 1;
    const int idA = side ? dst[eA] : src[eA];
    const int idB = side ? dst[eB] : src[eB];
    const float* fp = side ? df : sf;

    // ---- GEMM1: h = relu(c @ ew1 + b1), M=32, N=64, K=192 ----
    f32x4 acc[2][4];
    #pragma unroll
    for (int nt = 0; nt < 4; ++nt) {
        float bb = b1[nt * 16 + li];
        acc[0][nt] = splat4(bb);
        acc[1][nt] = splat4(bb);
    }
    #pragma unroll
    for (int ks = 0; ks < 6; ++ks) {
        bf16x8 a0, a1;
        if (ks < 4) {
            a0 = *(const bf16x8*)(nmbf + (size_t)idA * 128 + ks * 32 + q * 8);
            a1 = *(const bf16x8*)(nmbf + (size_t)idB * 128 + ks * 32 + q * 8);
        } else {
            const float* pA = fp + (size_t)eA * 64 + (ks - 4) * 32 + q * 8;
            const float* pB = fp + (size_t)eB * 64 + (ks - 4) * 32 + q * 8;
            a0 = cvt8(*(const float4*)pA, *(const float4*)(pA + 4));
            a1 = cvt8(*(const float4*)pB, *(const float4*)(pB + 4));
        }
        #pragma unroll
        for (int nt = 0; nt < 4; ++nt) {
            bf16x8 b = as_bf(ew1p[(size_t)(ks * 4 + nt) * 64 + l]);
            acc[0][nt] = mfma16(a0, b, acc[0][nt]);
            acc[1][nt] = mfma16(a1, b, acc[1][nt]);
        }
    }

    unsigned short* hw = hs + wv * 32 * 68;
    #pragma unroll
    for (int rt = 0; rt < 2; ++rt)
        #pragma unroll
        for (int nt = 0; nt < 4; ++nt)
            #pragma unroll
            for (int r = 0; r < 4; ++r)
                hw[(rt * 16 + q * 4 + r) * 68 + nt * 16 + li] =
                    f2bf(fmaxf(acc[rt][nt][r], 0.0f));

    // ---- GEMM2: emb = h @ ew2 + b2, K=64 ----
    f32x4 acc2[2][4];
    #pragma unroll
    for (int nt = 0; nt < 4; ++nt) {
        float bb = b2[nt * 16 + li];
        acc2[0][nt] = splat4(bb);
        acc2[1][nt] = splat4(bb);
    }
    #pragma unroll
    for (int ks = 0; ks < 2; ++ks) {
        bf16x8 a0 = lds8(hw + (li) * 68 + ks * 32 + q * 8);
        bf16x8 a1 = lds8(hw + (16 + li) * 68 + ks * 32 + q * 8);
        #pragma unroll
        for (int nt = 0; nt < 4; ++nt) {
            bf16x8 b = as_bf(ew2p[(size_t)(ks * 4 + nt) * 64 + l]);
            acc2[0][nt] = mfma16(a0, b, acc2[0][nt]);
            acc2[1][nt] = mfma16(a1, b, acc2[1][nt]);
        }
    }

    // stage emb fp32 in LDS: rows 0..63 = src, 64..127 = dst
    #pragma unroll
    for (int rt = 0; rt < 2; ++rt)
        #pragma unroll
        for (int nt = 0; nt < 4; ++nt)
            #pragma unroll
            for (int r = 0; r < 4; ++r)
                embs[(wv * 32 + rt * 16 + q * 4 + r) * 68 + nt * 16 + li] =
                    acc2[rt][nt][r];
    __syncthreads();

    if (tid < 64) {
        long long ge = e0 + tid;
        const float* pa = embs + tid * 68;
        const float* pb = embs + (64 + tid) * 68;
        float s = 0.0f;
        #pragma unroll
        for (int c = 0; c < 64; c += 4) {
            float4 va = *(const float4*)(pa + c);
            float4 vb = *(const float4*)(pb + c);
            s += va.x * vb.x + va.y * vb.y + va.z * vb.z + va.w * vb.w;
        }
        if (ge < E) out[ge] = s;
    }
}

// ---------------------------------------------------------------------------
extern "C" void kernel_launch(void* const* d_in, const int* in_sizes, int n_in,
                              void* d_out, int out_size, void* d_ws, size_t ws_size,
                              hipStream_t stream)
{
    const int*   src = (const int*)d_in[0];
    const int*   dst = (const int*)d_in[1];
    const float* ef  = (const float*)d_in[2];
    const float* ts  = (const float*)d_in[3];
    const float* sf  = (const float*)d_in[4];
    const float* df  = (const float*)d_in[5];
    const float* mem = (const float*)d_in[6];
    const float* tw  = (const float*)d_in[7];
    const float* tb  = (const float*)d_in[8];
    const float* mw1 = (const float*)d_in[9];
    const float* mb1 = (const float*)d_in[10];
    const float* mw2 = (const float*)d_in[11];
    const float* mb2 = (const float*)d_in[12];
    const float* wih = (const float*)d_in[13];
    const float* whh = (const float*)d_in[14];
    const float* bih = (const float*)d_in[15];
    const float* bhh = (const float*)d_in[16];
    const float* ew1 = (const float*)d_in[17];
    const float* eb1 = (const float*)d_in[18];
    const float* ew2 = (const float*)d_in[19];
    const float* eb2 = (const float*)d_in[20];

    const int E = in_sizes[0];
    const int N = in_sizes[6] / 128;

    size_t off = 0;
    auto carve = [&](size_t bytes) {
        size_t cur = off;
        off = (off + bytes + 255) & ~(size_t)255;
        return cur;
    };
    char* w = (char*)d_ws;
    int*            deg    = (int*)(w + carve((size_t)N * 4));        // also cursor
    int*            offs   = (int*)(w + carve((size_t)(N + 1) * 4));
    int*            elist  = (int*)(w + carve((size_t)2 * E * 4));
    unsigned short* membf  = (unsigned short*)(w + carve((size_t)N * 128 * 2));
    unsigned short* nmbf   = (unsigned short*)(w + carve((size_t)N * 128 * 2));
    unsigned short* msg    = (unsigned short*)(w + carve((size_t)E * 128 * 2));
    uint4*          packs  = (uint4*)(w + carve((size_t)336 * 64 * 16));

    const uint4* w1p  = packs;
    const uint4* w2p  = packs + (size_t)80 * 64;
    const uint4* wihp = packs + (size_t)112 * 64;
    const uint4* whhp = packs + (size_t)208 * 64;
    const uint4* ew1p = packs + (size_t)304 * 64;
    const uint4* ew2p = packs + (size_t)328 * 64;

    hipMemsetAsync(deg, 0, (size_t)N * 4, stream);

    k_hist<<<(E + 255) / 256, 256, 0, stream>>>(src, dst, deg, E);
    k_scan<<<1, 1024, 0, stream>>>(deg, offs, N);
    k_fill<<<(E + 255) / 256, 256, 0, stream>>>(src, dst, deg, elist, E);
    k_cvt<<<(N * 128 / 8 + 255) / 256, 256, 0, stream>>>(mem, membf, N * 128);
    k_pack<<<336, 64, 0, stream>>>(mw1, mw2, wih, whh, ew1, ew2, packs);

    k_edge_msg<<<(E + 127) / 128, 256, 0, stream>>>(src, dst, ef, ts, membf, tw, tb,
                                                    w1p, mb1, w2p, mb2, msg, E);
    k_gru<<<(N + 127) / 128, 256, 0, stream>>>(msg, offs, elist, membf, mem,
                                               wihp, whhp, bih, bhh, nmbf, N);
    k_embed<<<(E + 63) / 64, 256, 0, stream>>>(src, dst, sf, df, nmbf,
                                               ew1p, eb1, ew2p, eb2, (float*)d_out, E);
}

// Round 4
// 870.344 us; speedup vs baseline: 8.3620x; 1.2364x over previous
//
#include <hip/hip_runtime.h>
#include <math.h>

// ---------------------------------------------------------------------------
// TGN forward v4: bf16 MFMA + unordered-CSR (atomic bump allocation).
//   k_hist  : degree histogram
//   k_alloc : per-wave scan + one atomicAdd -> contiguous (unordered) regions
//   k_fill  : edge-list fill via cursor atomics (cursor = deg array)
//   k_cvt   : memory fp32 -> bf16 rows
//   k_pack  : pre-swizzle weights into MFMA B-fragment layout
//   k_edge_msg / k_gru / k_embed : MFMA compute kernels
// MFMA 16x16x32 bf16 layouts (HW-verified): A[m=l&15][k=(l>>4)*8+j],
// B[k=(l>>4)*8+j][n=l&15], D[m=(l>>4)*4+reg][n=l&15].
// ---------------------------------------------------------------------------

typedef __attribute__((ext_vector_type(8))) short bf16x8;
typedef __attribute__((ext_vector_type(4))) float f32x4;

static __device__ __forceinline__ unsigned short f2bf(float f) {
    unsigned int u = __float_as_uint(f);
    unsigned int r = (u + 0x7FFFu + ((u >> 16) & 1u)) >> 16;   // RNE
    return (unsigned short)r;
}
static __device__ __forceinline__ float bf2f(unsigned int v) {
    return __uint_as_float(v << 16);
}
static __device__ __forceinline__ bf16x8 as_bf(uint4 u) {
    union { uint4 u; bf16x8 v; } c; c.u = u; return c.v;
}
static __device__ __forceinline__ bf16x8 cvt8(float4 a, float4 b) {
    bf16x8 r;
    r[0]=(short)f2bf(a.x); r[1]=(short)f2bf(a.y); r[2]=(short)f2bf(a.z); r[3]=(short)f2bf(a.w);
    r[4]=(short)f2bf(b.x); r[5]=(short)f2bf(b.y); r[6]=(short)f2bf(b.z); r[7]=(short)f2bf(b.w);
    return r;
}
static __device__ __forceinline__ bf16x8 lds8(const unsigned short* p) {
    union { uint2 h[2]; bf16x8 v; } c;
    c.h[0] = *(const uint2*)p;
    c.h[1] = *(const uint2*)(p + 4);
    return c.v;
}
static __device__ __forceinline__ f32x4 mfma16(bf16x8 a, bf16x8 b, f32x4 c) {
    return __builtin_amdgcn_mfma_f32_16x16x32_bf16(a, b, c, 0, 0, 0);
}
static __device__ __forceinline__ f32x4 splat4(float v) {
    f32x4 c; c[0]=v; c[1]=v; c[2]=v; c[3]=v; return c;
}
static __device__ __forceinline__ float sigm(float x) {
    return 1.0f / (1.0f + expf(-x));
}

// ------------------------- CSR build ---------------------------------------
__global__ __launch_bounds__(256) void k_hist(const int* __restrict__ src,
                                              const int* __restrict__ dst,
                                              int* __restrict__ deg, int E) {
    int e = blockIdx.x * 256 + threadIdx.x;
    if (e < E) {
        atomicAdd(&deg[src[e]], 1);
        atomicAdd(&deg[dst[e]], 1);
    }
}

// Unordered contiguous region allocation: wave-scan + 1 atomicAdd per wave.
// Writes offs[i] = region base; overwrites deg[i] with base (fill cursor).
__global__ __launch_bounds__(256) void k_alloc(int* __restrict__ deg,
                                               int* __restrict__ offs,
                                               int* __restrict__ counter, int N) {
    int i = blockIdx.x * 256 + threadIdx.x;
    int l = threadIdx.x & 63;
    int d = (i < N) ? deg[i] : 0;
    int s = d;                              // inclusive wave scan
    #pragma unroll
    for (int o = 1; o < 64; o <<= 1) {
        int u = __shfl_up(s, o, 64);
        if (l >= o) s += u;
    }
    int total = __shfl(s, 63, 64);
    int base = 0;
    if (l == 63) base = atomicAdd(counter, total);
    base = __shfl(base, 63, 64);
    int my = base + s - d;
    if (i < N) { offs[i] = my; deg[i] = my; }
}

__global__ __launch_bounds__(256) void k_fill(const int* __restrict__ src,
                                              const int* __restrict__ dst,
                                              int* __restrict__ cursor,
                                              int* __restrict__ elist, int E) {
    int e = blockIdx.x * 256 + threadIdx.x;
    if (e < E) {
        int p = atomicAdd(&cursor[src[e]], 1);
        elist[p] = e;
        int q = atomicAdd(&cursor[dst[e]], 1);
        elist[q] = e;
    }
}

// ------------------------- fp32 -> bf16 ------------------------------------
__global__ __launch_bounds__(256) void k_cvt(const float* __restrict__ x,
                                             unsigned short* __restrict__ y, int n) {
    int i = (blockIdx.x * 256 + threadIdx.x) * 8;
    if (i < n) {
        float4 a = *(const float4*)&x[i];
        float4 b = *(const float4*)&x[i + 4];
        *(bf16x8*)&y[i] = cvt8(a, b);
    }
}

// ------------------------- weight pre-swizzle ------------------------------
// frag f, lane l -> 8 bf16 of B[k=kstep*32+(l>>4)*8+j][n=ntile*16+(l&15)].
// ranges: w1p 0..79 | w2p 80..111 | wihp 112..207 | whhp 208..303 |
//         ew1p 304..327 | ew2p 328..335
__global__ __launch_bounds__(64) void k_pack(
    const float* __restrict__ w1, const float* __restrict__ w2,
    const float* __restrict__ wih, const float* __restrict__ whh,
    const float* __restrict__ ew1, const float* __restrict__ ew2,
    uint4* __restrict__ out)
{
    int f = blockIdx.x, l = threadIdx.x;
    const float* srcp; int NT, sk, sn, base;
    if (f < 80)       { srcp = w1;  NT = 8;  sk = 128; sn = 1;   base = 0;   }
    else if (f < 112) { srcp = w2;  NT = 8;  sk = 128; sn = 1;   base = 80;  }
    else if (f < 208) { srcp = wih; NT = 24; sk = 1;   sn = 128; base = 112; }
    else if (f < 304) { srcp = whh; NT = 24; sk = 1;   sn = 128; base = 208; }
    else if (f < 328) { srcp = ew1; NT = 4;  sk = 64;  sn = 1;   base = 304; }
    else              { srcp = ew2; NT = 4;  sk = 64;  sn = 1;   base = 328; }
    int fl = f - base;
    int kstep = fl / NT, ntile = fl - kstep * NT;
    int n  = ntile * 16 + (l & 15);
    int k0 = kstep * 32 + (l >> 4) * 8;
    unsigned short h[8];
    #pragma unroll
    for (int j = 0; j < 8; ++j)
        h[j] = f2bf(srcp[(size_t)(k0 + j) * sk + (size_t)n * sn]);
    uint4 p;
    p.x = h[0] | ((unsigned)h[1] << 16);
    p.y = h[2] | ((unsigned)h[3] << 16);
    p.z = h[4] | ((unsigned)h[5] << 16);
    p.w = h[6] | ((unsigned)h[7] << 16);
    out[(size_t)f * 64 + l] = p;
}

// ------------------------- Kernel A: edge messages -------------------------
// 256 threads = 4 waves; wave handles 32 edges (2 MFMA row-tiles).
__global__ __launch_bounds__(256) void k_edge_msg(
    const int* __restrict__ src, const int* __restrict__ dst,
    const float* __restrict__ ef, const float* __restrict__ ts,
    const unsigned short* __restrict__ membf,
    const float* __restrict__ tw, const float* __restrict__ tb,
    const uint4* __restrict__ w1p, const float* __restrict__ b1,
    const uint4* __restrict__ w2p, const float* __restrict__ b2,
    unsigned short* __restrict__ msg, int E)
{
    __shared__ unsigned short h1s[4 * 32 * 132];
    const int tid = threadIdx.x;
    const int wv = tid >> 6, l = tid & 63;
    const int li = l & 15, q = l >> 4;
    const long long e0 = (long long)blockIdx.x * 128 + wv * 32;

    long long eA = e0 + li;       if (eA > E - 1) eA = E - 1;
    long long eB = e0 + 16 + li;  if (eB > E - 1) eB = E - 1;
    const int sA = src[eA], sB = src[eB], dA = dst[eA], dB = dst[eB];
    const float tsA = ts[eA], tsB = ts[eB];

    // ---- GEMM1: h1 = relu(x @ w1 + b1), M=32, N=128, K=320 ----
    f32x4 acc[2][8];
    #pragma unroll
    for (int nt = 0; nt < 8; ++nt) {
        float bb = b1[nt * 16 + li];
        acc[0][nt] = splat4(bb);
        acc[1][nt] = splat4(bb);
    }
    #pragma unroll
    for (int ks = 0; ks < 10; ++ks) {
        bf16x8 a0, a1;
        if (ks < 4) {
            a0 = *(const bf16x8*)(membf + (size_t)sA * 128 + ks * 32 + q * 8);
            a1 = *(const bf16x8*)(membf + (size_t)sB * 128 + ks * 32 + q * 8);
        } else if (ks < 8) {
            a0 = *(const bf16x8*)(membf + (size_t)dA * 128 + (ks - 4) * 32 + q * 8);
            a1 = *(const bf16x8*)(membf + (size_t)dB * 128 + (ks - 4) * 32 + q * 8);
        } else if (ks == 8) {
            const float* pA = ef + (size_t)eA * 32 + q * 8;
            const float* pB = ef + (size_t)eB * 32 + q * 8;
            a0 = cvt8(*(const float4*)pA, *(const float4*)(pA + 4));
            a1 = cvt8(*(const float4*)pB, *(const float4*)(pB + 4));
        } else {
            float4 twa = *(const float4*)&tw[q * 8];
            float4 twb = *(const float4*)&tw[q * 8 + 4];
            float4 tba = *(const float4*)&tb[q * 8];
            float4 tbb = *(const float4*)&tb[q * 8 + 4];
            float4 cA0, cA1, cB0, cB1;
            cA0.x = cosf(tsA*twa.x+tba.x); cA0.y = cosf(tsA*twa.y+tba.y);
            cA0.z = cosf(tsA*twa.z+tba.z); cA0.w = cosf(tsA*twa.w+tba.w);
            cA1.x = cosf(tsA*twb.x+tbb.x); cA1.y = cosf(tsA*twb.y+tbb.y);
            cA1.z = cosf(tsA*twb.z+tbb.z); cA1.w = cosf(tsA*twb.w+tbb.w);
            cB0.x = cosf(tsB*twa.x+tba.x); cB0.y = cosf(tsB*twa.y+tba.y);
            cB0.z = cosf(tsB*twa.z+tba.z); cB0.w = cosf(tsB*twa.w+tba.w);
            cB1.x = cosf(tsB*twb.x+tbb.x); cB1.y = cosf(tsB*twb.y+tbb.y);
            cB1.z = cosf(tsB*twb.z+tbb.z); cB1.w = cosf(tsB*twb.w+tbb.w);
            a0 = cvt8(cA0, cA1);
            a1 = cvt8(cB0, cB1);
        }
        #pragma unroll
        for (int nt = 0; nt < 8; ++nt) {
            bf16x8 b = as_bf(w1p[(size_t)(ks * 8 + nt) * 64 + l]);
            acc[0][nt] = mfma16(a0, b, acc[0][nt]);
            acc[1][nt] = mfma16(a1, b, acc[1][nt]);
        }
    }

    // relu -> wave-private LDS (C layout -> row-major [32][132])
    unsigned short* hw = h1s + wv * 32 * 132;
    #pragma unroll
    for (int rt = 0; rt < 2; ++rt)
        #pragma unroll
        for (int nt = 0; nt < 8; ++nt)
            #pragma unroll
            for (int r = 0; r < 4; ++r)
                hw[(rt * 16 + q * 4 + r) * 132 + nt * 16 + li] =
                    f2bf(fmaxf(acc[rt][nt][r], 0.0f));

    // ---- GEMM2: msg = h1 @ w2 + b2, K=128 ----
    f32x4 acc2[2][8];
    #pragma unroll
    for (int nt = 0; nt < 8; ++nt) {
        float bb = b2[nt * 16 + li];
        acc2[0][nt] = splat4(bb);
        acc2[1][nt] = splat4(bb);
    }
    #pragma unroll
    for (int ks = 0; ks < 4; ++ks) {
        bf16x8 a0 = lds8(hw + (li) * 132 + ks * 32 + q * 8);
        bf16x8 a1 = lds8(hw + (16 + li) * 132 + ks * 32 + q * 8);
        #pragma unroll
        for (int nt = 0; nt < 8; ++nt) {
            bf16x8 b = as_bf(w2p[(size_t)(ks * 8 + nt) * 64 + l]);
            acc2[0][nt] = mfma16(a0, b, acc2[0][nt]);
            acc2[1][nt] = mfma16(a1, b, acc2[1][nt]);
        }
    }

    // store bf16 msg rows
    #pragma unroll
    for (int rt = 0; rt < 2; ++rt)
        #pragma unroll
        for (int r = 0; r < 4; ++r) {
            long long ge = e0 + rt * 16 + q * 4 + r;
            if (ge < E) {
                #pragma unroll
                for (int nt = 0; nt < 8; ++nt)
                    msg[(size_t)ge * 128 + nt * 16 + li] = f2bf(acc2[rt][nt][r]);
            }
        }
}

// ------------------------- Kernel B: gather + GRU --------------------------
// 256 threads = 4 waves; block = 128 nodes; wave = 32 nodes (2 row-tiles).
// Region of node i is [offs[i], cur[i]) (cur = deg array after k_fill).
__global__ __launch_bounds__(256) void k_gru(
    const unsigned short* __restrict__ msg, const int* __restrict__ offs,
    const int* __restrict__ cur, const int* __restrict__ elist,
    const unsigned short* __restrict__ membf, const float* __restrict__ memf,
    const uint4* __restrict__ wihp, const uint4* __restrict__ whhp,
    const float* __restrict__ bih, const float* __restrict__ bhh,
    unsigned short* __restrict__ nmbf, int N)
{
    __shared__ unsigned short means[128 * 132];
    const int tid = threadIdx.x;
    const int n0 = blockIdx.x * 128;

    // ---- gather-mean: 4 threads/node, 32 cols each, 2 node-reps ----
    #pragma unroll
    for (int rep = 0; rep < 2; ++rep) {
        int nl = (tid >> 2) + rep * 64;
        int part = tid & 3;
        int node = n0 + nl;
        float acc[32];
        #pragma unroll
        for (int c = 0; c < 32; ++c) acc[c] = 0.0f;
        int a = 0, b = 0;
        if (node < N) { a = offs[node]; b = cur[node]; }
        for (int i = a; i < b; ++i) {
            int e = elist[i];
            const uint4* mr = (const uint4*)(msg + (size_t)e * 128 + part * 32);
            #pragma unroll
            for (int g = 0; g < 4; ++g) {
                uint4 u = mr[g];
                acc[g*8+0] += bf2f(u.x & 0xffffu); acc[g*8+1] += bf2f(u.x >> 16);
                acc[g*8+2] += bf2f(u.y & 0xffffu); acc[g*8+3] += bf2f(u.y >> 16);
                acc[g*8+4] += bf2f(u.z & 0xffffu); acc[g*8+5] += bf2f(u.z >> 16);
                acc[g*8+6] += bf2f(u.w & 0xffffu); acc[g*8+7] += bf2f(u.w >> 16);
            }
        }
        float inv = (b > a) ? 1.0f / (float)(b - a) : 0.0f;
        unsigned short* mp = means + nl * 132 + part * 32;
        #pragma unroll
        for (int g = 0; g < 8; ++g) {
            uint2 t2;
            t2.x = f2bf(acc[g*4+0]*inv) | ((unsigned)f2bf(acc[g*4+1]*inv) << 16);
            t2.y = f2bf(acc[g*4+2]*inv) | ((unsigned)f2bf(acc[g*4+3]*inv) << 16);
            *(uint2*)(mp + g * 4) = t2;
        }
    }
    __syncthreads();

    const int wv = tid >> 6, l = tid & 63;
    const int li = l & 15, q = l >> 4;
    const int nb = n0 + wv * 32;

    bf16x8 meanA[2][4], memA[2][4];
    #pragma unroll
    for (int rt = 0; rt < 2; ++rt) {
        int rowl = wv * 32 + rt * 16 + li;
        int node = min(n0 + rowl, N - 1);
        #pragma unroll
        for (int ks = 0; ks < 4; ++ks) {
            meanA[rt][ks] = lds8(means + rowl * 132 + ks * 32 + q * 8);
            memA[rt][ks]  = *(const bf16x8*)(membf + (size_t)node * 128 + ks * 32 + q * 8);
        }
    }

    int degv[2][4];
    #pragma unroll
    for (int rt = 0; rt < 2; ++rt)
        #pragma unroll
        for (int r = 0; r < 4; ++r) {
            int node = min(nb + rt * 16 + q * 4 + r, N - 1);
            degv[rt][r] = cur[node] - offs[node];
        }

    #pragma unroll
    for (int t = 0; t < 8; ++t) {
        f32x4 ai[2][3], ah[2][3];
        #pragma unroll
        for (int g = 0; g < 3; ++g) {
            float bi = bih[g * 128 + t * 16 + li];
            float bh = bhh[g * 128 + t * 16 + li];
            ai[0][g] = splat4(bi); ai[1][g] = splat4(bi);
            ah[0][g] = splat4(bh); ah[1][g] = splat4(bh);
        }
        #pragma unroll
        for (int ks = 0; ks < 4; ++ks) {
            #pragma unroll
            for (int g = 0; g < 3; ++g) {
                bf16x8 bi = as_bf(wihp[(size_t)(ks * 24 + t + g * 8) * 64 + l]);
                bf16x8 bh = as_bf(whhp[(size_t)(ks * 24 + t + g * 8) * 64 + l]);
                ai[0][g] = mfma16(meanA[0][ks], bi, ai[0][g]);
                ai[1][g] = mfma16(meanA[1][ks], bi, ai[1][g]);
                ah[0][g] = mfma16(memA[0][ks], bh, ah[0][g]);
                ah[1][g] = mfma16(memA[1][ks], bh, ah[1][g]);
            }
        }
        #pragma unroll
        for (int rt = 0; rt < 2; ++rt)
            #pragma unroll
            for (int r = 0; r < 4; ++r) {
                int node = nb + rt * 16 + q * 4 + r;
                int nc = min(node, N - 1);
                float hp = memf[(size_t)nc * 128 + t * 16 + li];
                float rg = sigm(ai[rt][0][r] + ah[rt][0][r]);
                float zg = sigm(ai[rt][1][r] + ah[rt][1][r]);
                float ng = tanhf(ai[rt][2][r] + rg * ah[rt][2][r]);
                float hnew = (degv[rt][r] > 0) ? (1.0f - zg) * ng + zg * hp : hp;
                if (node < N)
                    nmbf[(size_t)node * 128 + t * 16 + li] = f2bf(hnew);
            }
    }
}

// ------------------------- Kernel C: embeddings + dot ----------------------
// 256 threads = 4 waves; block = 64 edges; waves 0,1 = src rows, 2,3 = dst.
__global__ __launch_bounds__(256) void k_embed(
    const int* __restrict__ src, const int* __restrict__ dst,
    const float* __restrict__ sf, const float* __restrict__ df,
    const unsigned short* __restrict__ nmbf,
    const uint4* __restrict__ ew1p, const float* __restrict__ b1,
    const uint4* __restrict__ ew2p, const float* __restrict__ b2,
    float* __restrict__ out, int E)
{
    __shared__ float embs[128 * 68];
    __shared__ unsigned short hs[4 * 32 * 68];
    const int tid = threadIdx.x;
    const int wv = tid >> 6, l = tid & 63;
    const int li = l & 15, q = l >> 4;
    const long long e0 = (long long)blockIdx.x * 64;

    const int side = wv >> 1;
    long long eA = e0 + (wv & 1) * 32 + li;      if (eA > E - 1) eA = E - 1;
    long long eB = e0 + (wv & 1) * 32 + 16 + li; if (eB > E - 1) eB = E - 1;
    const int idA = side ? dst[eA] : src[eA];
    const int idB = side ? dst[eB] : src[eB];
    const float* fp = side ? df : sf;

    // ---- GEMM1: h = relu(c @ ew1 + b1), M=32, N=64, K=192 ----
    f32x4 acc[2][4];
    #pragma unroll
    for (int nt = 0; nt < 4; ++nt) {
        float bb = b1[nt * 16 + li];
        acc[0][nt] = splat4(bb);
        acc[1][nt] = splat4(bb);
    }
    #pragma unroll
    for (int ks = 0; ks < 6; ++ks) {
        bf16x8 a0, a1;
        if (ks < 4) {
            a0 = *(const bf16x8*)(nmbf + (size_t)idA * 128 + ks * 32 + q * 8);
            a1 = *(const bf16x8*)(nmbf + (size_t)idB * 128 + ks * 32 + q * 8);
        } else {
            const float* pA = fp + (size_t)eA * 64 + (ks - 4) * 32 + q * 8;
            const float* pB = fp + (size_t)eB * 64 + (ks - 4) * 32 + q * 8;
            a0 = cvt8(*(const float4*)pA, *(const float4*)(pA + 4));
            a1 = cvt8(*(const float4*)pB, *(const float4*)(pB + 4));
        }
        #pragma unroll
        for (int nt = 0; nt < 4; ++nt) {
            bf16x8 b = as_bf(ew1p[(size_t)(ks * 4 + nt) * 64 + l]);
            acc[0][nt] = mfma16(a0, b, acc[0][nt]);
            acc[1][nt] = mfma16(a1, b, acc[1][nt]);
        }
    }

    unsigned short* hw = hs + wv * 32 * 68;
    #pragma unroll
    for (int rt = 0; rt < 2; ++rt)
        #pragma unroll
        for (int nt = 0; nt < 4; ++nt)
            #pragma unroll
            for (int r = 0; r < 4; ++r)
                hw[(rt * 16 + q * 4 + r) * 68 + nt * 16 + li] =
                    f2bf(fmaxf(acc[rt][nt][r], 0.0f));

    // ---- GEMM2: emb = h @ ew2 + b2, K=64 ----
    f32x4 acc2[2][4];
    #pragma unroll
    for (int nt = 0; nt < 4; ++nt) {
        float bb = b2[nt * 16 + li];
        acc2[0][nt] = splat4(bb);
        acc2[1][nt] = splat4(bb);
    }
    #pragma unroll
    for (int ks = 0; ks < 2; ++ks) {
        bf16x8 a0 = lds8(hw + (li) * 68 + ks * 32 + q * 8);
        bf16x8 a1 = lds8(hw + (16 + li) * 68 + ks * 32 + q * 8);
        #pragma unroll
        for (int nt = 0; nt < 4; ++nt) {
            bf16x8 b = as_bf(ew2p[(size_t)(ks * 4 + nt) * 64 + l]);
            acc2[0][nt] = mfma16(a0, b, acc2[0][nt]);
            acc2[1][nt] = mfma16(a1, b, acc2[1][nt]);
        }
    }

    // stage emb fp32 in LDS: rows 0..63 = src, 64..127 = dst
    #pragma unroll
    for (int rt = 0; rt < 2; ++rt)
        #pragma unroll
        for (int nt = 0; nt < 4; ++nt)
            #pragma unroll
            for (int r = 0; r < 4; ++r)
                embs[(wv * 32 + rt * 16 + q * 4 + r) * 68 + nt * 16 + li] =
                    acc2[rt][nt][r];
    __syncthreads();

    if (tid < 64) {
        long long ge = e0 + tid;
        const float* pa = embs + tid * 68;
        const float* pb = embs + (64 + tid) * 68;
        float s = 0.0f;
        #pragma unroll
        for (int c = 0; c < 64; c += 4) {
            float4 va = *(const float4*)(pa + c);
            float4 vb = *(const float4*)(pb + c);
            s += va.x * vb.x + va.y * vb.y + va.z * vb.z + va.w * vb.w;
        }
        if (ge < E) out[ge] = s;
    }
}

// ---------------------------------------------------------------------------
extern "C" void kernel_launch(void* const* d_in, const int* in_sizes, int n_in,
                              void* d_out, int out_size, void* d_ws, size_t ws_size,
                              hipStream_t stream)
{
    const int*   src = (const int*)d_in[0];
    const int*   dst = (const int*)d_in[1];
    const float* ef  = (const float*)d_in[2];
    const float* ts  = (const float*)d_in[3];
    const float* sf  = (const float*)d_in[4];
    const float* df  = (const float*)d_in[5];
    const float* mem = (const float*)d_in[6];
    const float* tw  = (const float*)d_in[7];
    const float* tb  = (const float*)d_in[8];
    const float* mw1 = (const float*)d_in[9];
    const float* mb1 = (const float*)d_in[10];
    const float* mw2 = (const float*)d_in[11];
    const float* mb2 = (const float*)d_in[12];
    const float* wih = (const float*)d_in[13];
    const float* whh = (const float*)d_in[14];
    const float* bih = (const float*)d_in[15];
    const float* bhh = (const float*)d_in[16];
    const float* ew1 = (const float*)d_in[17];
    const float* eb1 = (const float*)d_in[18];
    const float* ew2 = (const float*)d_in[19];
    const float* eb2 = (const float*)d_in[20];

    const int E = in_sizes[0];
    const int N = in_sizes[6] / 128;

    size_t off = 0;
    auto carve = [&](size_t bytes) {
        size_t cur = off;
        off = (off + bytes + 255) & ~(size_t)255;
        return cur;
    };
    char* w = (char*)d_ws;
    int*            deg    = (int*)(w + carve((size_t)N * 4));        // also cursor
    int*            offs   = (int*)(w + carve((size_t)N * 4));
    int*            counter= (int*)(w + carve(256));
    int*            elist  = (int*)(w + carve((size_t)2 * E * 4));
    unsigned short* membf  = (unsigned short*)(w + carve((size_t)N * 128 * 2));
    unsigned short* nmbf   = (unsigned short*)(w + carve((size_t)N * 128 * 2));
    unsigned short* msg    = (unsigned short*)(w + carve((size_t)E * 128 * 2));
    uint4*          packs  = (uint4*)(w + carve((size_t)336 * 64 * 16));

    const uint4* w1p  = packs;
    const uint4* w2p  = packs + (size_t)80 * 64;
    const uint4* wihp = packs + (size_t)112 * 64;
    const uint4* whhp = packs + (size_t)208 * 64;
    const uint4* ew1p = packs + (size_t)304 * 64;
    const uint4* ew2p = packs + (size_t)328 * 64;

    hipMemsetAsync(deg, 0, (size_t)N * 4, stream);
    hipMemsetAsync(counter, 0, 4, stream);

    k_hist<<<(E + 255) / 256, 256, 0, stream>>>(src, dst, deg, E);
    k_alloc<<<(N + 255) / 256, 256, 0, stream>>>(deg, offs, counter, N);
    k_fill<<<(E + 255) / 256, 256, 0, stream>>>(src, dst, deg, elist, E);
    k_cvt<<<(N * 128 / 8 + 255) / 256, 256, 0, stream>>>(mem, membf, N * 128);
    k_pack<<<336, 64, 0, stream>>>(mw1, mw2, wih, whh, ew1, ew2, packs);

    k_edge_msg<<<(E + 127) / 128, 256, 0, stream>>>(src, dst, ef, ts, membf, tw, tb,
                                                    w1p, mb1, w2p, mb2, msg, E);
    k_gru<<<(N + 127) / 128, 256, 0, stream>>>(msg, offs, deg, elist, membf, mem,
                                               wihp, whhp, bih, bhh, nmbf, N);
    k_embed<<<(E + 63) / 64, 256, 0, stream>>>(src, dst, sf, df, nmbf,
                                               ew1p, eb1, ew2p, eb2, (float*)d_out, E);
}